// Round 10
// baseline (3486.204 us; speedup 1.0000x reference)
//
#include <hip/hip_runtime.h>
#include <hip/hip_bf16.h>
#include <stdint.h>

typedef __bf16 bf16x8 __attribute__((ext_vector_type(8)));
typedef __bf16 bf16x4 __attribute__((ext_vector_type(4)));
typedef float  f32x4  __attribute__((ext_vector_type(4)));

#define DIN   128
#define KA    384
#define HD    512
#define NB    1152
#define DOUTD 128
#define NOBJ  50000
#define NTRI  200000
#define TM    64
#define NSCAN 98   // ceil(NOBJ/512)
#define SB_STRIDE 520

// ---------------- edges normalization (int32/int64 auto-detect, clamp) ----------------
__global__ void detect_i64(const int* __restrict__ e, int* __restrict__ flag) {
    int i = blockIdx.x * 256 + threadIdx.x;
    if (i < NTRI && e[2 * i + 1] != 0) atomicOr(flag, 1);   // odd words nonzero => int32 layout
}
__global__ void normalize_edges(const int* __restrict__ e, const int* __restrict__ flag,
                                int* __restrict__ sidx, int* __restrict__ oidx) {
    int t = blockIdx.x * 256 + threadIdx.x;
    if (t >= NTRI) return;
    bool is64 = (*flag == 0);
    int s = is64 ? e[4 * t]     : e[2 * t];
    int o = is64 ? e[4 * t + 2] : e[2 * t + 1];
    s = s < 0 ? 0 : (s >= NOBJ ? NOBJ - 1 : s);
    o = o < 0 ? 0 : (o >= NOBJ ? NOBJ - 1 : o);
    sidx[t] = s; oidx[t] = o;
}

// ---------------- weight packing: f32 row-major (K,N) -> bf16 MFMA B-fragments ----------------
__global__ void pack_w(const float* __restrict__ W, __bf16* __restrict__ P, int K, int N) {
    int idx = blockIdx.x * 256 + threadIdx.x;
    int total = (K / 32) * (N / 16) * 64;
    if (idx >= total) return;
    int lane = idx & 63;
    int f    = idx >> 6;
    int NT   = N / 16;
    int kt = f / NT, nt = f - kt * NT;
    int krow = kt * 32 + (lane >> 4) * 8;
    int col  = nt * 16 + (lane & 15);
    __bf16 tmp[8];
#pragma unroll
    for (int i = 0; i < 8; i++) tmp[i] = (__bf16)W[(size_t)(krow + i) * N + col];
    *reinterpret_cast<bf16x8*>(P + (size_t)idx * 8) = *reinterpret_cast<const bf16x8*>(tmp);
}

// ---------------- degree counts ----------------
__global__ void count_int(const int* __restrict__ sidx, const int* __restrict__ oidx,
                          int* __restrict__ cnt) {
    int t = blockIdx.x * 256 + threadIdx.x;
    if (t >= NTRI) return;
    atomicAdd(&cnt[sidx[t]], 1);
    atomicAdd(&cnt[oidx[t]], 1);
}

// ---------------- CSR prefix scan ----------------
__global__ void scanA(const int* __restrict__ cnt, int* __restrict__ sums) {
    __shared__ int sh[512];
    int idx = blockIdx.x * 512 + threadIdx.x;
    sh[threadIdx.x] = idx < NOBJ ? cnt[idx] : 0;
    __syncthreads();
    for (int s = 256; s > 0; s >>= 1) {
        if (threadIdx.x < s) sh[threadIdx.x] += sh[threadIdx.x + s];
        __syncthreads();
    }
    if (threadIdx.x == 0) sums[blockIdx.x] = sh[0];
}
__global__ void scanB(int* __restrict__ sums) {
    if (threadIdx.x == 0) {
        int run = 0;
        for (int i = 0; i < NSCAN; i++) { int v = sums[i]; sums[i] = run; run += v; }
    }
}
__global__ void scanC(const int* __restrict__ cnt, const int* __restrict__ sums,
                      int* __restrict__ offs, int* __restrict__ cursor) {
    __shared__ int sh[512];
    int idx = blockIdx.x * 512 + threadIdx.x;
    int v = idx < NOBJ ? cnt[idx] : 0;
    sh[threadIdx.x] = v;
    __syncthreads();
    for (int d = 1; d < 512; d <<= 1) {
        int t = (threadIdx.x >= d) ? sh[threadIdx.x - d] : 0;
        __syncthreads();
        sh[threadIdx.x] += t;
        __syncthreads();
    }
    if (idx < NOBJ) {
        int excl = sh[threadIdx.x] - v + sums[blockIdx.x];
        offs[idx] = excl; cursor[idx] = excl;
    }
}
__global__ void fill_refs(const int* __restrict__ sidx, const int* __restrict__ oidx,
                          int* __restrict__ cursor, int* __restrict__ refs) {
    int t = blockIdx.x * 256 + threadIdx.x;
    if (t >= NTRI) return;
    int p = atomicAdd(&cursor[sidx[t]], 1); refs[p] = 2 * t;
    int q = atomicAdd(&cursor[oidx[t]], 1); refs[q] = 2 * t + 1;
}

// ---------------- pooling: CSR gather mean -> x (bf16) ----------------
__global__ __launch_bounds__(512) void pool_mean(
    const __bf16* __restrict__ newso, const int* __restrict__ cnt,
    const int* __restrict__ offs, const int* __restrict__ refs,
    __bf16* __restrict__ xbuf)
{
    int w    = (blockIdx.x * 512 + threadIdx.x) >> 6;   // one wave per object
    int lane = threadIdx.x & 63;
    if (w >= NOBJ) return;
    int n = cnt[w], off = offs[w];
    float acc[8];
#pragma unroll
    for (int i = 0; i < 8; i++) acc[i] = 0.f;
    for (int j = 0; j < n; j++) {
        int r = refs[off + j];
        const __bf16* src = newso + (size_t)(r >> 1) * 1024 + (r & 1) * 512 + lane * 8;
        bf16x8 v = *reinterpret_cast<const bf16x8*>(src);
#pragma unroll
        for (int i = 0; i < 8; i++) acc[i] += (float)v[i];
    }
    float inv = 1.f / (n > 0 ? (float)n : 1.f);
    bf16x8 o;
#pragma unroll
    for (int i = 0; i < 8; i++) o[i] = (__bf16)(acc[i] * inv);
    *reinterpret_cast<bf16x8*>(xbuf + (size_t)w * 512 + lane * 8) = o;
}

// ---------------- fused GEMM1 + GEMM2, templated for ablation ----------------
// MODE 0: full.  1: no gather.  2: no B loads (const frag).  3: stores behind runtime-false.
// MODE 4: no LDS A-reads (const A frag).
template<int MODE>
__global__ __launch_bounds__(512, 4) void fused12(
    const float* __restrict__ obj, const float* __restrict__ pred,
    const int* __restrict__ sidx, const int* __restrict__ oidx,
    const __bf16* __restrict__ pW1a, const float* __restrict__ b1a,
    const __bf16* __restrict__ pW1b, const float* __restrict__ b1b,
    float* __restrict__ out_p, __bf16* __restrict__ newso, int never)
{
    extern __shared__ char smem[];
    __bf16* sB = (__bf16*)smem;                          // 64*520*2 = 66560 B

    const int tid  = threadIdx.x;
    const int lane = tid & 63;
    const int wn   = tid >> 6;          // 0..7 : N-slice owner
    const int t0   = blockIdx.x * TM;

    const int lk    = (lane >> 4) * 8;
    const int lr    = lane & 15;
    const int rbase = (lane >> 4) * 4;

    bf16x8 cfrag;
#pragma unroll
    for (int i = 0; i < 8; i++) cfrag[i] = (__bf16)0.5f;

    // ---- Phase 1: gather cur_t tile (f32 -> bf16) into LDS ----
    if constexpr (MODE != 1) {
        for (int u = tid; u < 64 * 96; u += 512) {
            int part = u & 31;
            int seg  = (u >> 5) % 3;
            int row  = u / 96;
            int t    = t0 + row;
            const float* src;
            if (seg == 0)      src = obj  + (size_t)sidx[t] * DIN;
            else if (seg == 1) src = pred + (size_t)t       * DIN;
            else               src = obj  + (size_t)oidx[t] * DIN;
            float4 v = *reinterpret_cast<const float4*>(src + part * 4);
            bf16x4 w;
            w[0] = (__bf16)v.x; w[1] = (__bf16)v.y; w[2] = (__bf16)v.z; w[3] = (__bf16)v.w;
            *reinterpret_cast<bf16x4*>(sB + row * SB_STRIDE + seg * 128 + part * 4) = w;
        }
    }
    __syncthreads();

    // ---- GEMM1: h = relu(cur_t @ W1a + b1a) ----
    {
        f32x4 acc[4][4];
#pragma unroll
        for (int mi = 0; mi < 4; mi++)
#pragma unroll
            for (int ni = 0; ni < 4; ni++) acc[mi][ni] = (f32x4){0.f, 0.f, 0.f, 0.f};

        for (int kt = 0; kt < KA / 32; ++kt) {
            bf16x8 b[4];
#pragma unroll
            for (int ni = 0; ni < 4; ni++) {
                if constexpr (MODE == 2) b[ni] = cfrag;
                else b[ni] = *reinterpret_cast<const bf16x8*>(pW1a + (((size_t)(kt * 32 + wn * 4 + ni)) * 64 + lane) * 8);
            }
            bf16x8 a[4];
#pragma unroll
            for (int mi = 0; mi < 4; mi++) {
                if constexpr (MODE == 4) a[mi] = cfrag;
                else a[mi] = *reinterpret_cast<const bf16x8*>(sB + (mi * 16 + lr) * SB_STRIDE + kt * 32 + lk);
            }
#pragma unroll
            for (int ni = 0; ni < 4; ni++)
#pragma unroll
                for (int mi = 0; mi < 4; mi++)
                    acc[mi][ni] = __builtin_amdgcn_mfma_f32_16x16x32_bf16(a[mi], b[ni], acc[mi][ni], 0, 0, 0);
        }
        __syncthreads();

        // epilogue: bias + relu -> sB (h, bf16)  (kept in all modes: feeds GEMM2)
#pragma unroll
        for (int ni = 0; ni < 4; ni++) {
            int col = wn * 64 + ni * 16 + lr;
            float bv = b1a[col];
#pragma unroll
            for (int mi = 0; mi < 4; mi++)
#pragma unroll
                for (int r = 0; r < 4; r++) {
                    float v = acc[mi][ni][r] + bv;
                    v = v > 0.f ? v : 0.f;
                    sB[(mi * 16 + rbase + r) * SB_STRIDE + col] = (__bf16)v;
                }
        }
    }
    __syncthreads();

    // ---- GEMM2: new_t = relu(h @ W1b + b1b); 3 N-passes ----
    for (int pp = 0; pp < 3; ++pp) {
        f32x4 acc2[4][3];
#pragma unroll
        for (int mi = 0; mi < 4; mi++)
#pragma unroll
            for (int ni = 0; ni < 3; ni++) acc2[mi][ni] = (f32x4){0.f, 0.f, 0.f, 0.f};

        for (int kt = 0; kt < HD / 32; ++kt) {
            bf16x8 b[3];
#pragma unroll
            for (int ni = 0; ni < 3; ni++) {
                if constexpr (MODE == 2) b[ni] = cfrag;
                else b[ni] = *reinterpret_cast<const bf16x8*>(pW1b + (((size_t)(kt * 72 + wn * 9 + pp * 3 + ni)) * 64 + lane) * 8);
            }
            bf16x8 a[4];
#pragma unroll
            for (int mi = 0; mi < 4; mi++) {
                if constexpr (MODE == 4) a[mi] = cfrag;
                else a[mi] = *reinterpret_cast<const bf16x8*>(sB + (mi * 16 + lr) * SB_STRIDE + kt * 32 + lk);
            }
#pragma unroll
            for (int ni = 0; ni < 3; ni++)
#pragma unroll
                for (int mi = 0; mi < 4; mi++)
                    acc2[mi][ni] = __builtin_amdgcn_mfma_f32_16x16x32_bf16(a[mi], b[ni], acc2[mi][ni], 0, 0, 0);
        }
        // epilogue: bias + relu, route
        bool do_store = (MODE != 3) || never;
#pragma unroll
        for (int ni = 0; ni < 3; ni++) {
            int c = wn * 144 + pp * 48 + ni * 16 + lr;
            float bv = b1b[c];
#pragma unroll
            for (int mi = 0; mi < 4; mi++)
#pragma unroll
                for (int r = 0; r < 4; r++) {
                    int row = mi * 16 + rbase + r;
                    int t   = t0 + row;
                    float v = acc2[mi][ni][r] + bv;
                    v = v > 0.f ? v : 0.f;
                    if (do_store) {
                        if (c < HD) {
                            newso[(size_t)t * 1024 + c] = (__bf16)v;
                        } else if (c < HD + DOUTD) {
                            out_p[(size_t)t * DOUTD + (c - HD)] = v;
                        } else {
                            newso[(size_t)t * 1024 + 512 + (c - HD - DOUTD)] = (__bf16)v;
                        }
                    }
                }
        }
    }
}

// ---------------- fused GEMM3 + GEMM4 (aliased LDS) ----------------
__global__ __launch_bounds__(512, 4) void fused34(
    const __bf16* __restrict__ xbuf,
    const __bf16* __restrict__ pW2a, const float* __restrict__ b2a,
    const __bf16* __restrict__ pW2b, const float* __restrict__ b2b,
    float* __restrict__ out_obj)
{
    extern __shared__ char smem[];
    __bf16* sX = (__bf16*)smem;                          // 64*520*2 (x, then h2)

    const int tid  = threadIdx.x;
    const int lane = tid & 63;
    const int wid  = tid >> 6;
    const int o0   = blockIdx.x * TM;

    for (int u = tid; u < 64 * 64; u += 512) {
        int part = u & 63;
        int row  = u >> 6;
        int ob   = o0 + row;
        bf16x8 v;
        if (ob < NOBJ) v = *reinterpret_cast<const bf16x8*>(xbuf + (size_t)ob * 512 + part * 8);
        else { bf16x8 z = {}; v = z; }
        *reinterpret_cast<bf16x8*>(sX + row * SB_STRIDE + part * 8) = v;
    }
    __syncthreads();

    const int wm = wid >> 2;
    const int wn = wid & 3;
    const int lk = (lane >> 4) * 8;
    const int lr = lane & 15;
    const int rbase = (lane >> 4) * 4;

    {
        f32x4 acc[2][8];
#pragma unroll
        for (int mi = 0; mi < 2; mi++)
#pragma unroll
            for (int ni = 0; ni < 8; ni++) acc[mi][ni] = (f32x4){0.f, 0.f, 0.f, 0.f};

        for (int kt = 0; kt < HD / 32; ++kt) {
            bf16x8 a0 = *reinterpret_cast<const bf16x8*>(sX + (wm * 32 + lr) * SB_STRIDE + kt * 32 + lk);
            bf16x8 a1 = *reinterpret_cast<const bf16x8*>(sX + (wm * 32 + 16 + lr) * SB_STRIDE + kt * 32 + lk);
#pragma unroll
            for (int ni = 0; ni < 8; ni++) {
                bf16x8 b = *reinterpret_cast<const bf16x8*>(pW2a + (((size_t)(kt * 32 + wn * 8 + ni)) * 64 + lane) * 8);
                acc[0][ni] = __builtin_amdgcn_mfma_f32_16x16x32_bf16(a0, b, acc[0][ni], 0, 0, 0);
                acc[1][ni] = __builtin_amdgcn_mfma_f32_16x16x32_bf16(a1, b, acc[1][ni], 0, 0, 0);
            }
        }
        __syncthreads();

#pragma unroll
        for (int mi = 0; mi < 2; mi++)
#pragma unroll
            for (int ni = 0; ni < 8; ni++) {
                int col = wn * 128 + ni * 16 + lr;
                float bv = b2a[col];
#pragma unroll
                for (int r = 0; r < 4; r++) {
                    float v = acc[mi][ni][r] + bv;
                    v = v > 0.f ? v : 0.f;
                    sX[(wm * 32 + mi * 16 + rbase + r) * SB_STRIDE + col] = (__bf16)v;
                }
            }
    }
    __syncthreads();

    {
        f32x4 acc[2][2];
#pragma unroll
        for (int mi = 0; mi < 2; mi++)
#pragma unroll
            for (int ni = 0; ni < 2; ni++) acc[mi][ni] = (f32x4){0.f, 0.f, 0.f, 0.f};

        for (int kt = 0; kt < HD / 32; ++kt) {
            bf16x8 a0 = *reinterpret_cast<const bf16x8*>(sX + (wm * 32 + lr) * SB_STRIDE + kt * 32 + lk);
            bf16x8 a1 = *reinterpret_cast<const bf16x8*>(sX + (wm * 32 + 16 + lr) * SB_STRIDE + kt * 32 + lk);
#pragma unroll
            for (int ni = 0; ni < 2; ni++) {
                int f = kt * 8 + wn * 2 + ni;
                bf16x8 b = *reinterpret_cast<const bf16x8*>(pW2b + ((size_t)f * 64 + lane) * 8);
                acc[0][ni] = __builtin_amdgcn_mfma_f32_16x16x32_bf16(a0, b, acc[0][ni], 0, 0, 0);
                acc[1][ni] = __builtin_amdgcn_mfma_f32_16x16x32_bf16(a1, b, acc[1][ni], 0, 0, 0);
            }
        }
#pragma unroll
        for (int mi = 0; mi < 2; mi++)
#pragma unroll
            for (int ni = 0; ni < 2; ni++) {
                int col = wn * 32 + ni * 16 + lr;
                float bv = b2b[col];
#pragma unroll
                for (int r = 0; r < 4; r++) {
                    int row = wm * 32 + mi * 16 + rbase + r;
                    int ob  = o0 + row;
                    if (ob < NOBJ) {
                        float v = acc[mi][ni][r] + bv;
                        v = v > 0.f ? v : 0.f;
                        out_obj[(size_t)ob * DOUTD + col] = v;
                    }
                }
            }
    }
}

// ---------------- launch ----------------
extern "C" void kernel_launch(void* const* d_in, const int* in_sizes, int n_in,
                              void* d_out, int out_size, void* d_ws, size_t ws_size,
                              hipStream_t stream)
{
    const float* obj   = (const float*)d_in[0];
    const float* pred  = (const float*)d_in[1];
    const int*   edges = (const int*)d_in[2];
    const float* W1a = (const float*)d_in[3];
    const float* b1a = (const float*)d_in[4];
    const float* W1b = (const float*)d_in[5];
    const float* b1b = (const float*)d_in[6];
    const float* W2a = (const float*)d_in[7];
    const float* b2a = (const float*)d_in[8];
    const float* W2b = (const float*)d_in[9];
    const float* b2b = (const float*)d_in[10];

    float* out_obj = (float*)d_out;
    float* out_p   = (float*)d_out + (size_t)NOBJ * DOUTD;

    char* ws = (char*)d_ws;
    int*    sidx   = (int*)ws;
    int*    oidx   = sidx + NTRI;
    int*    flag   = (int*)(ws + 1800000);
    __bf16* pW1a   = (__bf16*)(ws + 1800064);
    __bf16* pW1b   = pW1a + 196608;
    __bf16* pW2a   = pW1b + 589824;
    __bf16* pW2b   = pW2a + 262144;
    int*    cnt    = (int*)(ws + 4028416);
    int*    offs   = (int*)(ws + 4228416);
    int*    cursor = (int*)(ws + 4428416);
    int*    sums   = (int*)(ws + 4628416);
    int*    refs   = (int*)(ws + 4628928);
    __bf16* xbuf   = (__bf16*)(ws + 6228928);
    __bf16* newso  = (__bf16*)(ws + 57428928);

    hipMemsetAsync(flag, 0, 4, stream);
    detect_i64<<<(NTRI + 255) / 256, 256, 0, stream>>>(edges, flag);
    normalize_edges<<<(NTRI + 255) / 256, 256, 0, stream>>>(edges, flag, sidx, oidx);

    pack_w<<<(24576 + 255) / 256, 256, 0, stream>>>(W1a, pW1a, 384, 512);
    pack_w<<<(73728 + 255) / 256, 256, 0, stream>>>(W1b, pW1b, 512, 1152);
    pack_w<<<(32768 + 255) / 256, 256, 0, stream>>>(W2a, pW2a, 512, 512);
    pack_w<<<(8192  + 255) / 256, 256, 0, stream>>>(W2b, pW2b, 512, 128);

    hipMemsetAsync(cnt, 0, 200000, stream);
    count_int<<<(NTRI + 255) / 256, 256, 0, stream>>>(sidx, oidx, cnt);
    scanA<<<NSCAN, 512, 0, stream>>>(cnt, sums);
    scanB<<<1, 64, 0, stream>>>(sums);
    scanC<<<NSCAN, 512, 0, stream>>>(cnt, sums, offs, cursor);
    fill_refs<<<(NTRI + 255) / 256, 256, 0, stream>>>(sidx, oidx, cursor, refs);

    size_t lds12 = (size_t)64 * SB_STRIDE * 2;           // 66560

    // ======== ABLATION DISPATCHES (diagnostic; outputs overwritten by real run below) ========
    fused12<0><<<NTRI / TM, 512, lds12, stream>>>(obj, pred, sidx, oidx, pW1a, b1a, pW1b, b1b, out_p, newso, 0);
    fused12<1><<<NTRI / TM, 512, lds12, stream>>>(obj, pred, sidx, oidx, pW1a, b1a, pW1b, b1b, out_p, newso, 0);
    fused12<2><<<NTRI / TM, 512, lds12, stream>>>(obj, pred, sidx, oidx, pW1a, b1a, pW1b, b1b, out_p, newso, 0);
    fused12<3><<<NTRI / TM, 512, lds12, stream>>>(obj, pred, sidx, oidx, pW1a, b1a, pW1b, b1b, out_p, newso, 0);
    fused12<4><<<NTRI / TM, 512, lds12, stream>>>(obj, pred, sidx, oidx, pW1a, b1a, pW1b, b1b, out_p, newso, 0);

    // ======== REAL PIPELINE (runs last; overwrites every byte the ablations touched) ========
    fused12<0><<<NTRI / TM, 512, lds12, stream>>>(obj, pred, sidx, oidx, pW1a, b1a, pW1b, b1b, out_p, newso, 0);
    pool_mean<<<(NOBJ * 64 + 511) / 512, 512, 0, stream>>>(newso, cnt, offs, refs, xbuf);
    fused34<<<(NOBJ + TM - 1) / TM, 512, lds12, stream>>>(xbuf, pW2a, b2a, pW2b, b2b, out_obj);
}

// Round 11
// 1047.230 us; speedup vs baseline: 3.3290x; 3.3290x over previous
//
#include <hip/hip_runtime.h>
#include <hip/hip_bf16.h>
#include <stdint.h>

typedef __bf16 bf16x8 __attribute__((ext_vector_type(8)));
typedef __bf16 bf16x4 __attribute__((ext_vector_type(4)));
typedef float  f32x4  __attribute__((ext_vector_type(4)));

#define DIN   128
#define KA    384
#define HD    512
#define NB    1152
#define DOUTD 128
#define NOBJ  50000
#define NTRI  200000
#define NSCAN 98   // ceil(NOBJ/512)
#define SB_STRIDE 520

// ---- async 16B global->LDS DMA (gfx950 global_load_lds_dwordx4) ----
__device__ __forceinline__ void gload16(const void* g, void* l) {
    __builtin_amdgcn_global_load_lds(
        (const __attribute__((address_space(1))) void*)g,
        (__attribute__((address_space(3))) void*)l, 16, 0, 0);
}

// ---------------- edges normalization (int32/int64 auto-detect, clamp) ----------------
__global__ void detect_i64(const int* __restrict__ e, int* __restrict__ flag) {
    int i = blockIdx.x * 256 + threadIdx.x;
    if (i < NTRI && e[2 * i + 1] != 0) atomicOr(flag, 1);
}
__global__ void normalize_edges(const int* __restrict__ e, const int* __restrict__ flag,
                                int* __restrict__ sidx, int* __restrict__ oidx) {
    int t = blockIdx.x * 256 + threadIdx.x;
    if (t >= NTRI) return;
    bool is64 = (*flag == 0);
    int s = is64 ? e[4 * t]     : e[2 * t];
    int o = is64 ? e[4 * t + 2] : e[2 * t + 1];
    s = s < 0 ? 0 : (s >= NOBJ ? NOBJ - 1 : s);
    o = o < 0 ? 0 : (o >= NOBJ ? NOBJ - 1 : o);
    sidx[t] = s; oidx[t] = o;
}

// ---------------- f32 -> bf16 bulk convert ----------------
__global__ void to_bf16(const float* __restrict__ in, __bf16* __restrict__ out, long n4) {
    long i = (long)blockIdx.x * 256 + threadIdx.x;
    long stride = (long)gridDim.x * 256;
    for (; i < n4; i += stride) {
        float4 v = reinterpret_cast<const float4*>(in)[i];
        bf16x4 w;
        w[0] = (__bf16)v.x; w[1] = (__bf16)v.y; w[2] = (__bf16)v.z; w[3] = (__bf16)v.w;
        reinterpret_cast<bf16x4*>(out)[i] = w;
    }
}

// ---------------- weight packing: f32 row-major (K,N) -> bf16 MFMA B-fragments ----------------
__global__ void pack_w(const float* __restrict__ W, __bf16* __restrict__ P, int K, int N) {
    int idx = blockIdx.x * 256 + threadIdx.x;
    int total = (K / 32) * (N / 16) * 64;
    if (idx >= total) return;
    int lane = idx & 63;
    int f    = idx >> 6;
    int NT   = N / 16;
    int kt = f / NT, nt = f - kt * NT;
    int krow = kt * 32 + (lane >> 4) * 8;
    int col  = nt * 16 + (lane & 15);
    __bf16 tmp[8];
#pragma unroll
    for (int i = 0; i < 8; i++) tmp[i] = (__bf16)W[(size_t)(krow + i) * N + col];
    *reinterpret_cast<bf16x8*>(P + (size_t)idx * 8) = *reinterpret_cast<const bf16x8*>(tmp);
}

// ---------------- degree counts / CSR ----------------
__global__ void count_int(const int* __restrict__ sidx, const int* __restrict__ oidx,
                          int* __restrict__ cnt) {
    int t = blockIdx.x * 256 + threadIdx.x;
    if (t >= NTRI) return;
    atomicAdd(&cnt[sidx[t]], 1);
    atomicAdd(&cnt[oidx[t]], 1);
}
__global__ void scanA(const int* __restrict__ cnt, int* __restrict__ sums) {
    __shared__ int sh[512];
    int idx = blockIdx.x * 512 + threadIdx.x;
    sh[threadIdx.x] = idx < NOBJ ? cnt[idx] : 0;
    __syncthreads();
    for (int s = 256; s > 0; s >>= 1) {
        if (threadIdx.x < s) sh[threadIdx.x] += sh[threadIdx.x + s];
        __syncthreads();
    }
    if (threadIdx.x == 0) sums[blockIdx.x] = sh[0];
}
__global__ void scanB(int* __restrict__ sums) {
    if (threadIdx.x == 0) {
        int run = 0;
        for (int i = 0; i < NSCAN; i++) { int v = sums[i]; sums[i] = run; run += v; }
    }
}
__global__ void scanC(const int* __restrict__ cnt, const int* __restrict__ sums,
                      int* __restrict__ offs, int* __restrict__ cursor) {
    __shared__ int sh[512];
    int idx = blockIdx.x * 512 + threadIdx.x;
    int v = idx < NOBJ ? cnt[idx] : 0;
    sh[threadIdx.x] = v;
    __syncthreads();
    for (int d = 1; d < 512; d <<= 1) {
        int t = (threadIdx.x >= d) ? sh[threadIdx.x - d] : 0;
        __syncthreads();
        sh[threadIdx.x] += t;
        __syncthreads();
    }
    if (idx < NOBJ) {
        int excl = sh[threadIdx.x] - v + sums[blockIdx.x];
        offs[idx] = excl; cursor[idx] = excl;
    }
}
__global__ void fill_refs(const int* __restrict__ sidx, const int* __restrict__ oidx,
                          int* __restrict__ cursor, int* __restrict__ refs) {
    int t = blockIdx.x * 256 + threadIdx.x;
    if (t >= NTRI) return;
    int p = atomicAdd(&cursor[sidx[t]], 1); refs[p] = 2 * t;
    int q = atomicAdd(&cursor[oidx[t]], 1); refs[q] = 2 * t + 1;
}

// ---------------- pooling: CSR gather mean -> x (bf16) ----------------
__global__ __launch_bounds__(512) void pool_mean(
    const __bf16* __restrict__ newso, const int* __restrict__ cnt,
    const int* __restrict__ offs, const int* __restrict__ refs,
    __bf16* __restrict__ xbuf)
{
    int w    = (blockIdx.x * 512 + threadIdx.x) >> 6;
    int lane = threadIdx.x & 63;
    if (w >= NOBJ) return;
    int n = cnt[w], off = offs[w];
    float acc[8];
#pragma unroll
    for (int i = 0; i < 8; i++) acc[i] = 0.f;
    for (int j = 0; j < n; j++) {
        int r = refs[off + j];
        const __bf16* src = newso + (size_t)(r >> 1) * 1024 + (r & 1) * 512 + lane * 8;
        bf16x8 v = *reinterpret_cast<const bf16x8*>(src);
#pragma unroll
        for (int i = 0; i < 8; i++) acc[i] += (float)v[i];
    }
    float inv = 1.f / (n > 0 ? (float)n : 1.f);
    bf16x8 o;
#pragma unroll
    for (int i = 0; i < 8; i++) o[i] = (__bf16)(acc[i] * inv);
    *reinterpret_cast<bf16x8*>(xbuf + (size_t)w * 512 + lane * 8) = o;
}

// ================= m97-style GEMM1: h = relu(cur_t @ W1a + b1a) =================
// grid (ceil(NTRI/128), 4). tile 128x128, BK=32, 4 waves (2m x 2n), 64x64/wave.
// A gathered+staged via global_load_lds from pre-converted bf16 obj/pred.
// B staged via global_load_lds from fragment-ordered pW1a (linear LDS dest).
__global__ __launch_bounds__(256, 3) void gemm1(
    const __bf16* __restrict__ objbf, const __bf16* __restrict__ predbf,
    const int* __restrict__ sidx, const int* __restrict__ oidx,
    const __bf16* __restrict__ pW1a, const float* __restrict__ b1a,
    __bf16* __restrict__ hbuf)
{
    __shared__ char smem[32768];
    char* sA = smem;            // [2][128 rows][64 B]    (8 KB per buf)
    char* sB = smem + 16384;    // [2][8 frags][1024 B]

    const int tid = threadIdx.x, lane = tid & 63, wid = tid >> 6;
    const int wm = wid >> 1, wn = wid & 1;
    const int t0 = blockIdx.x * 128;
    const int nb = blockIdx.y;

    // per-lane staging precompute: wave wid handles issues i0=2*wid, i1=2*wid+1
    const int i0 = 2 * wid, i1 = i0 + 1;
    int trA0 = t0 + i0 * 16 + (lane >> 2); if (trA0 >= NTRI) trA0 = NTRI - 1;
    int trA1 = t0 + i1 * 16 + (lane >> 2); if (trA1 >= NTRI) trA1 = NTRI - 1;
    const int cb0 = (lane & 3) * 16;   // byte offset of this lane's 16B chunk within 64B
    const char* srcS0 = (const char*)(objbf  + (size_t)sidx[trA0] * DIN) + cb0;
    const char* srcP0 = (const char*)(predbf + (size_t)trA0 * DIN) + cb0;
    const char* srcO0 = (const char*)(objbf  + (size_t)oidx[trA0] * DIN) + cb0;
    const char* srcS1 = (const char*)(objbf  + (size_t)sidx[trA1] * DIN) + cb0;
    const char* srcP1 = (const char*)(predbf + (size_t)trA1 * DIN) + cb0;
    const char* srcO1 = (const char*)(objbf  + (size_t)oidx[trA1] * DIN) + cb0;
    const char* pWc   = (const char*)pW1a + (size_t)lane * 16;

    f32x4 acc[4][4];
#pragma unroll
    for (int mi = 0; mi < 4; mi++)
#pragma unroll
        for (int ni = 0; ni < 4; ni++) acc[mi][ni] = (f32x4){0.f, 0.f, 0.f, 0.f};

    auto stage = [&](int buf, int kt) {
        int third = kt >> 2;                    // 0:obj[s] 1:pred 2:obj[o]
        int cb = (kt & 3) * 64;                 // byte offset within the 256B source row
        const char* g0 = (third == 0 ? srcS0 : third == 1 ? srcP0 : srcO0) + cb;
        const char* g1 = (third == 0 ? srcS1 : third == 1 ? srcP1 : srcO1) + cb;
        gload16(g0, sA + buf * 8192 + i0 * 1024);
        gload16(g1, sA + buf * 8192 + i1 * 1024);
        const char* gb0 = pWc + (size_t)(kt * 32 + nb * 8 + i0) * 1024;
        const char* gb1 = pWc + (size_t)(kt * 32 + nb * 8 + i1) * 1024;
        gload16(gb0, sB + buf * 8192 + i0 * 1024);
        gload16(gb1, sB + buf * 8192 + i1 * 1024);
    };

    int buf = 0;
    stage(0, 0);
    __syncthreads();
    for (int kt = 0; kt < KA / 32; ++kt) {
        if (kt + 1 < KA / 32) stage(buf ^ 1, kt + 1);
        const char* aB = sA + buf * 8192;
        const char* bB = sB + buf * 8192;
        bf16x8 af[4], bf[4];
#pragma unroll
        for (int mi = 0; mi < 4; mi++) {
            int row = wm * 64 + mi * 16 + (lane & 15);
            af[mi] = *reinterpret_cast<const bf16x8*>(aB + row * 64 + (lane >> 4) * 16);
        }
#pragma unroll
        for (int ni = 0; ni < 4; ni++)
            bf[ni] = *reinterpret_cast<const bf16x8*>(bB + (wn * 4 + ni) * 1024 + lane * 16);
#pragma unroll
        for (int ni = 0; ni < 4; ni++)
#pragma unroll
            for (int mi = 0; mi < 4; mi++)
                acc[mi][ni] = __builtin_amdgcn_mfma_f32_16x16x32_bf16(af[mi], bf[ni], acc[mi][ni], 0, 0, 0);
        __syncthreads();
        buf ^= 1;
    }

    // epilogue: bias + relu -> hbuf (bf16)
#pragma unroll
    for (int ni = 0; ni < 4; ni++) {
        int colg = nb * 128 + wn * 64 + ni * 16 + (lane & 15);
        float bv = b1a[colg];
#pragma unroll
        for (int mi = 0; mi < 4; mi++)
#pragma unroll
            for (int r = 0; r < 4; r++) {
                int trow = t0 + wm * 64 + mi * 16 + (lane >> 4) * 4 + r;
                if (trow < NTRI) {
                    float v = acc[mi][ni][r] + bv;
                    v = v > 0.f ? v : 0.f;
                    hbuf[(size_t)trow * HD + colg] = (__bf16)v;
                }
            }
    }
}

// ================= m97-style GEMM2: new_t = relu(h @ W1b + b1b) =================
// grid (ceil(NTRI/128), 9). Per-block uniform routing: nb<4 -> new_s, nb==4 -> out_p, nb>4 -> new_o.
__global__ __launch_bounds__(256, 3) void gemm2(
    const __bf16* __restrict__ hbuf,
    const __bf16* __restrict__ pW1b, const float* __restrict__ b1b,
    float* __restrict__ out_p, __bf16* __restrict__ newso)
{
    __shared__ char smem[32768];
    char* sA = smem;
    char* sB = smem + 16384;

    const int tid = threadIdx.x, lane = tid & 63, wid = tid >> 6;
    const int wm = wid >> 1, wn = wid & 1;
    const int t0 = blockIdx.x * 128;
    const int nb = blockIdx.y;

    const int i0 = 2 * wid, i1 = i0 + 1;
    int trA0 = t0 + i0 * 16 + (lane >> 2); if (trA0 >= NTRI) trA0 = NTRI - 1;
    int trA1 = t0 + i1 * 16 + (lane >> 2); if (trA1 >= NTRI) trA1 = NTRI - 1;
    const int cb0 = (lane & 3) * 16;
    const char* srcH0 = (const char*)(hbuf + (size_t)trA0 * HD) + cb0;
    const char* srcH1 = (const char*)(hbuf + (size_t)trA1 * HD) + cb0;
    const char* pWc   = (const char*)pW1b + (size_t)lane * 16;

    f32x4 acc[4][4];
#pragma unroll
    for (int mi = 0; mi < 4; mi++)
#pragma unroll
        for (int ni = 0; ni < 4; ni++) acc[mi][ni] = (f32x4){0.f, 0.f, 0.f, 0.f};

    auto stage = [&](int buf, int kt) {
        int cb = kt * 64;                       // 16 kts x 64B = 1024B row ✓
        gload16(srcH0 + cb, sA + buf * 8192 + i0 * 1024);
        gload16(srcH1 + cb, sA + buf * 8192 + i1 * 1024);
        const char* gb0 = pWc + (size_t)(kt * 72 + nb * 8 + i0) * 1024;
        const char* gb1 = pWc + (size_t)(kt * 72 + nb * 8 + i1) * 1024;
        gload16(gb0, sB + buf * 8192 + i0 * 1024);
        gload16(gb1, sB + buf * 8192 + i1 * 1024);
    };

    int buf = 0;
    stage(0, 0);
    __syncthreads();
    for (int kt = 0; kt < HD / 32; ++kt) {
        if (kt + 1 < HD / 32) stage(buf ^ 1, kt + 1);
        const char* aB = sA + buf * 8192;
        const char* bB = sB + buf * 8192;
        bf16x8 af[4], bf[4];
#pragma unroll
        for (int mi = 0; mi < 4; mi++) {
            int row = wm * 64 + mi * 16 + (lane & 15);
            af[mi] = *reinterpret_cast<const bf16x8*>(aB + row * 64 + (lane >> 4) * 16);
        }
#pragma unroll
        for (int ni = 0; ni < 4; ni++)
            bf[ni] = *reinterpret_cast<const bf16x8*>(bB + (wn * 4 + ni) * 1024 + lane * 16);
#pragma unroll
        for (int ni = 0; ni < 4; ni++)
#pragma unroll
            for (int mi = 0; mi < 4; mi++)
                acc[mi][ni] = __builtin_amdgcn_mfma_f32_16x16x32_bf16(af[mi], bf[ni], acc[mi][ni], 0, 0, 0);
        __syncthreads();
        buf ^= 1;
    }

#pragma unroll
    for (int ni = 0; ni < 4; ni++) {
        int colg = nb * 128 + wn * 64 + ni * 16 + (lane & 15);
        float bv = b1b[colg];
#pragma unroll
        for (int mi = 0; mi < 4; mi++)
#pragma unroll
            for (int r = 0; r < 4; r++) {
                int trow = t0 + wm * 64 + mi * 16 + (lane >> 4) * 4 + r;
                if (trow < NTRI) {
                    float v = acc[mi][ni][r] + bv;
                    v = v > 0.f ? v : 0.f;
                    if (nb < 4)       newso[(size_t)trow * 1024 + colg] = (__bf16)v;
                    else if (nb == 4) out_p[(size_t)trow * DOUTD + (colg - HD)] = v;
                    else              newso[(size_t)trow * 1024 + 512 + (colg - 640)] = (__bf16)v;
                }
            }
    }
}

// ---------------- legacy fused GEMM1+GEMM2 (R9 fallback) ----------------
__global__ __launch_bounds__(512, 4) void fused12_legacy(
    const float* __restrict__ obj, const float* __restrict__ pred,
    const int* __restrict__ sidx, const int* __restrict__ oidx,
    const __bf16* __restrict__ pW1a, const float* __restrict__ b1a,
    const __bf16* __restrict__ pW1b, const float* __restrict__ b1b,
    float* __restrict__ out_p, __bf16* __restrict__ newso)
{
    extern __shared__ char smem[];
    __bf16* sB = (__bf16*)smem;

    const int tid  = threadIdx.x;
    const int lane = tid & 63;
    const int wn   = tid >> 6;
    const int t0   = blockIdx.x * 64;

    const int lk    = (lane >> 4) * 8;
    const int lr    = lane & 15;
    const int rbase = (lane >> 4) * 4;

    for (int u = tid; u < 64 * 96; u += 512) {
        int part = u & 31;
        int seg  = (u >> 5) % 3;
        int row  = u / 96;
        int t    = t0 + row;
        const float* src;
        if (seg == 0)      src = obj  + (size_t)sidx[t] * DIN;
        else if (seg == 1) src = pred + (size_t)t       * DIN;
        else               src = obj  + (size_t)oidx[t] * DIN;
        float4 v = *reinterpret_cast<const float4*>(src + part * 4);
        bf16x4 w;
        w[0] = (__bf16)v.x; w[1] = (__bf16)v.y; w[2] = (__bf16)v.z; w[3] = (__bf16)v.w;
        *reinterpret_cast<bf16x4*>(sB + row * SB_STRIDE + seg * 128 + part * 4) = w;
    }
    __syncthreads();

    {
        f32x4 acc[4][4];
#pragma unroll
        for (int mi = 0; mi < 4; mi++)
#pragma unroll
            for (int ni = 0; ni < 4; ni++) acc[mi][ni] = (f32x4){0.f, 0.f, 0.f, 0.f};

        for (int kt = 0; kt < KA / 32; ++kt) {
            bf16x8 a[4];
#pragma unroll
            for (int mi = 0; mi < 4; mi++)
                a[mi] = *reinterpret_cast<const bf16x8*>(sB + (mi * 16 + lr) * SB_STRIDE + kt * 32 + lk);
#pragma unroll
            for (int ni = 0; ni < 4; ni++) {
                bf16x8 b = *reinterpret_cast<const bf16x8*>(pW1a + (((size_t)(kt * 32 + wn * 4 + ni)) * 64 + lane) * 8);
#pragma unroll
                for (int mi = 0; mi < 4; mi++)
                    acc[mi][ni] = __builtin_amdgcn_mfma_f32_16x16x32_bf16(a[mi], b, acc[mi][ni], 0, 0, 0);
            }
        }
        __syncthreads();
#pragma unroll
        for (int ni = 0; ni < 4; ni++) {
            int col = wn * 64 + ni * 16 + lr;
            float bv = b1a[col];
#pragma unroll
            for (int mi = 0; mi < 4; mi++)
#pragma unroll
                for (int r = 0; r < 4; r++) {
                    float v = acc[mi][ni][r] + bv;
                    v = v > 0.f ? v : 0.f;
                    sB[(mi * 16 + rbase + r) * SB_STRIDE + col] = (__bf16)v;
                }
        }
    }
    __syncthreads();

    for (int pp = 0; pp < 3; ++pp) {
        f32x4 acc2[4][3];
#pragma unroll
        for (int mi = 0; mi < 4; mi++)
#pragma unroll
            for (int ni = 0; ni < 3; ni++) acc2[mi][ni] = (f32x4){0.f, 0.f, 0.f, 0.f};

        for (int kt = 0; kt < HD / 32; ++kt) {
            bf16x8 a[4];
#pragma unroll
            for (int mi = 0; mi < 4; mi++)
                a[mi] = *reinterpret_cast<const bf16x8*>(sB + (mi * 16 + lr) * SB_STRIDE + kt * 32 + lk);
#pragma unroll
            for (int ni = 0; ni < 3; ni++) {
                bf16x8 b = *reinterpret_cast<const bf16x8*>(pW1b + (((size_t)(kt * 72 + wn * 9 + pp * 3 + ni)) * 64 + lane) * 8);
#pragma unroll
                for (int mi = 0; mi < 4; mi++)
                    acc2[mi][ni] = __builtin_amdgcn_mfma_f32_16x16x32_bf16(a[mi], b, acc2[mi][ni], 0, 0, 0);
            }
        }
#pragma unroll
        for (int ni = 0; ni < 3; ni++) {
            int c = wn * 144 + pp * 48 + ni * 16 + lr;
            float bv = b1b[c];
#pragma unroll
            for (int mi = 0; mi < 4; mi++)
#pragma unroll
                for (int r = 0; r < 4; r++) {
                    int row = mi * 16 + rbase + r;
                    int t   = t0 + row;
                    float v = acc2[mi][ni][r] + bv;
                    v = v > 0.f ? v : 0.f;
                    if (c < HD) newso[(size_t)t * 1024 + c] = (__bf16)v;
                    else if (c < HD + DOUTD) out_p[(size_t)t * DOUTD + (c - HD)] = v;
                    else newso[(size_t)t * 1024 + 512 + (c - HD - DOUTD)] = (__bf16)v;
                }
        }
    }
}

// ---------------- fused GEMM3 + GEMM4 (aliased LDS) ----------------
__global__ __launch_bounds__(512, 4) void fused34(
    const __bf16* __restrict__ xbuf,
    const __bf16* __restrict__ pW2a, const float* __restrict__ b2a,
    const __bf16* __restrict__ pW2b, const float* __restrict__ b2b,
    float* __restrict__ out_obj)
{
    extern __shared__ char smem[];
    __bf16* sX = (__bf16*)smem;

    const int tid  = threadIdx.x;
    const int lane = tid & 63;
    const int wid  = tid >> 6;
    const int o0   = blockIdx.x * 64;

    for (int u = tid; u < 64 * 64; u += 512) {
        int part = u & 63;
        int row  = u >> 6;
        int ob   = o0 + row;
        bf16x8 v;
        if (ob < NOBJ) v = *reinterpret_cast<const bf16x8*>(xbuf + (size_t)ob * 512 + part * 8);
        else { bf16x8 z = {}; v = z; }
        *reinterpret_cast<bf16x8*>(sX + row * SB_STRIDE + part * 8) = v;
    }
    __syncthreads();

    const int wm = wid >> 2;
    const int wn = wid & 3;
    const int lk = (lane >> 4) * 8;
    const int lr = lane & 15;
    const int rbase = (lane >> 4) * 4;

    {
        f32x4 acc[2][8];
#pragma unroll
        for (int mi = 0; mi < 2; mi++)
#pragma unroll
            for (int ni = 0; ni < 8; ni++) acc[mi][ni] = (f32x4){0.f, 0.f, 0.f, 0.f};

        for (int kt = 0; kt < HD / 32; ++kt) {
            bf16x8 a0 = *reinterpret_cast<const bf16x8*>(sX + (wm * 32 + lr) * SB_STRIDE + kt * 32 + lk);
            bf16x8 a1 = *reinterpret_cast<const bf16x8*>(sX + (wm * 32 + 16 + lr) * SB_STRIDE + kt * 32 + lk);
#pragma unroll
            for (int ni = 0; ni < 8; ni++) {
                bf16x8 b = *reinterpret_cast<const bf16x8*>(pW2a + (((size_t)(kt * 32 + wn * 8 + ni)) * 64 + lane) * 8);
                acc[0][ni] = __builtin_amdgcn_mfma_f32_16x16x32_bf16(a0, b, acc[0][ni], 0, 0, 0);
                acc[1][ni] = __builtin_amdgcn_mfma_f32_16x16x32_bf16(a1, b, acc[1][ni], 0, 0, 0);
            }
        }
        __syncthreads();

#pragma unroll
        for (int mi = 0; mi < 2; mi++)
#pragma unroll
            for (int ni = 0; ni < 8; ni++) {
                int col = wn * 128 + ni * 16 + lr;
                float bv = b2a[col];
#pragma unroll
                for (int r = 0; r < 4; r++) {
                    float v = acc[mi][ni][r] + bv;
                    v = v > 0.f ? v : 0.f;
                    sX[(wm * 32 + mi * 16 + rbase + r) * SB_STRIDE + col] = (__bf16)v;
                }
            }
    }
    __syncthreads();

    {
        f32x4 acc[2][2];
#pragma unroll
        for (int mi = 0; mi < 2; mi++)
#pragma unroll
            for (int ni = 0; ni < 2; ni++) acc[mi][ni] = (f32x4){0.f, 0.f, 0.f, 0.f};

        for (int kt = 0; kt < HD / 32; ++kt) {
            bf16x8 a0 = *reinterpret_cast<const bf16x8*>(sX + (wm * 32 + lr) * SB_STRIDE + kt * 32 + lk);
            bf16x8 a1 = *reinterpret_cast<const bf16x8*>(sX + (wm * 32 + 16 + lr) * SB_STRIDE + kt * 32 + lk);
#pragma unroll
            for (int ni = 0; ni < 2; ni++) {
                int f = kt * 8 + wn * 2 + ni;
                bf16x8 b = *reinterpret_cast<const bf16x8*>(pW2b + ((size_t)f * 64 + lane) * 8);
                acc[0][ni] = __builtin_amdgcn_mfma_f32_16x16x32_bf16(a0, b, acc[0][ni], 0, 0, 0);
                acc[1][ni] = __builtin_amdgcn_mfma_f32_16x16x32_bf16(a1, b, acc[1][ni], 0, 0, 0);
            }
        }
#pragma unroll
        for (int mi = 0; mi < 2; mi++)
#pragma unroll
            for (int ni = 0; ni < 2; ni++) {
                int col = wn * 32 + ni * 16 + lr;
                float bv = b2b[col];
#pragma unroll
                for (int r = 0; r < 4; r++) {
                    int row = wm * 32 + mi * 16 + rbase + r;
                    int ob  = o0 + row;
                    if (ob < NOBJ) {
                        float v = acc[mi][ni][r] + bv;
                        v = v > 0.f ? v : 0.f;
                        out_obj[(size_t)ob * DOUTD + col] = v;
                    }
                }
            }
    }
}

// ---------------- launch ----------------
extern "C" void kernel_launch(void* const* d_in, const int* in_sizes, int n_in,
                              void* d_out, int out_size, void* d_ws, size_t ws_size,
                              hipStream_t stream)
{
    const float* obj   = (const float*)d_in[0];
    const float* pred  = (const float*)d_in[1];
    const int*   edges = (const int*)d_in[2];
    const float* W1a = (const float*)d_in[3];
    const float* b1a = (const float*)d_in[4];
    const float* W1b = (const float*)d_in[5];
    const float* b1b = (const float*)d_in[6];
    const float* W2a = (const float*)d_in[7];
    const float* b2a = (const float*)d_in[8];
    const float* W2b = (const float*)d_in[9];
    const float* b2b = (const float*)d_in[10];

    float* out_obj = (float*)d_out;
    float* out_p   = (float*)d_out + (size_t)NOBJ * DOUTD;

    // ws layout (bytes):
    // base (proven ≥ 467,028,928): sidx/oidx/flag/packedW/cnt/offs/cursor/sums/refs/xbuf/newso
    // fast extras: objbf @467,028,928 (12.8MB) ; predbf @479,828,928 (51.2MB) ; hbuf @531,028,928 (204.8MB)
    char* ws = (char*)d_ws;
    int*    sidx   = (int*)ws;
    int*    oidx   = sidx + NTRI;
    int*    flag   = (int*)(ws + 1800000);
    __bf16* pW1a   = (__bf16*)(ws + 1800064);
    __bf16* pW1b   = pW1a + 196608;
    __bf16* pW2a   = pW1b + 589824;
    __bf16* pW2b   = pW2a + 262144;
    int*    cnt    = (int*)(ws + 4028416);
    int*    offs   = (int*)(ws + 4228416);
    int*    cursor = (int*)(ws + 4428416);
    int*    sums   = (int*)(ws + 4628416);
    int*    refs   = (int*)(ws + 4628928);
    __bf16* xbuf   = (__bf16*)(ws + 6228928);
    __bf16* newso  = (__bf16*)(ws + 57428928);
    __bf16* objbf  = (__bf16*)(ws + 467028928);
    __bf16* predbf = (__bf16*)(ws + 479828928);
    __bf16* hbuf   = (__bf16*)(ws + 531028928);
    const size_t NEED_M97 = 735828928;

    bool m97 = ws_size >= NEED_M97;

    hipMemsetAsync(flag, 0, 4, stream);
    detect_i64<<<(NTRI + 255) / 256, 256, 0, stream>>>(edges, flag);
    normalize_edges<<<(NTRI + 255) / 256, 256, 0, stream>>>(edges, flag, sidx, oidx);

    pack_w<<<(24576 + 255) / 256, 256, 0, stream>>>(W1a, pW1a, 384, 512);
    pack_w<<<(73728 + 255) / 256, 256, 0, stream>>>(W1b, pW1b, 512, 1152);
    pack_w<<<(32768 + 255) / 256, 256, 0, stream>>>(W2a, pW2a, 512, 512);
    pack_w<<<(8192  + 255) / 256, 256, 0, stream>>>(W2b, pW2b, 512, 128);

    hipMemsetAsync(cnt, 0, 200000, stream);
    count_int<<<(NTRI + 255) / 256, 256, 0, stream>>>(sidx, oidx, cnt);
    scanA<<<NSCAN, 512, 0, stream>>>(cnt, sums);
    scanB<<<1, 64, 0, stream>>>(sums);
    scanC<<<NSCAN, 512, 0, stream>>>(cnt, sums, offs, cursor);
    fill_refs<<<(NTRI + 255) / 256, 256, 0, stream>>>(sidx, oidx, cursor, refs);

    if (m97) {
        to_bf16<<<2048, 256, 0, stream>>>(obj,  objbf,  (long)NOBJ * DIN / 4);
        to_bf16<<<2048, 256, 0, stream>>>(pred, predbf, (long)NTRI * DIN / 4);
        dim3 g1((NTRI + 127) / 128, 4);
        gemm1<<<g1, 256, 0, stream>>>(objbf, predbf, sidx, oidx, pW1a, b1a, hbuf);
        dim3 g2((NTRI + 127) / 128, 9);
        gemm2<<<g2, 256, 0, stream>>>(hbuf, pW1b, b1b, out_p, newso);
    } else {
        size_t lds12 = (size_t)64 * SB_STRIDE * 2;
        fused12_legacy<<<NTRI / 64, 512, lds12, stream>>>(obj, pred, sidx, oidx,
                                                          pW1a, b1a, pW1b, b1b,
                                                          out_p, newso);
    }

    pool_mean<<<(NOBJ * 64 + 511) / 512, 512, 0, stream>>>(newso, cnt, offs, refs, xbuf);
    size_t lds34 = (size_t)64 * SB_STRIDE * 2;
    fused34<<<(NOBJ + 63) / 64, 512, lds34, stream>>>(xbuf, pW2a, b2a, pW2b, b2b, out_obj);
}